// Round 1
// baseline (788.456 us; speedup 1.0000x reference)
//
#include <hip/hip_runtime.h>
#include <hip/hip_bf16.h>
#include <cstdint>

typedef __hip_bfloat16 bf16;
typedef __bf16 b8 __attribute__((ext_vector_type(8)));
typedef float f4v __attribute__((ext_vector_type(4)));

#define DEVI static __device__ __forceinline__

// async global->LDS, 16B per lane. LDS dest is wave-uniform base + lane*16,
// so callers MUST pass lds slots that are contiguous in lane order.
DEVI void gload16(const void* g, void* l) {
  __builtin_amdgcn_global_load_lds(
      (const __attribute__((address_space(1))) void*)(uintptr_t)g,
      (__attribute__((address_space(3))) void*)(uint32_t)(uintptr_t)l,
      16, 0, 0);
}

DEVI f4v mfma_bf16(b8 a, b8 b, f4v c) {
  return __builtin_amdgcn_mfma_f32_16x16x32_bf16(a, b, c, 0, 0, 0);
}

// ---------------------------------------------------------------------------
// prep: x -> cur (fp32 copy) + curb (bf16)
// ---------------------------------------------------------------------------
__global__ void prep_kernel(const float* __restrict__ x, float* __restrict__ cur,
                            bf16* __restrict__ curb) {
  int i = (blockIdx.x * 256 + threadIdx.x) * 4;
  float4 v = *(const float4*)(x + i);
  *(float4*)(cur + i) = v;
  __hip_bfloat162 a, b;
  a.x = __float2bfloat16(v.x); a.y = __float2bfloat16(v.y);
  b.x = __float2bfloat16(v.z); b.y = __float2bfloat16(v.w);
  *(__hip_bfloat162*)(curb + i) = a;
  *(__hip_bfloat162*)(curb + i + 2) = b;
}

// ---------------------------------------------------------------------------
// transpose + cast fp32 [R][C] -> bf16 [C][R]   (weights, tiny)
// ---------------------------------------------------------------------------
__global__ void transpose_cast(const float* __restrict__ in, bf16* __restrict__ out,
                               int R, int C) {
  __shared__ float tile[32][33];
  int c0 = blockIdx.x * 32, r0 = blockIdx.y * 32;
  int tx = threadIdx.x & 31, ty = threadIdx.x >> 5;  // 32 x 8
  for (int rr = ty; rr < 32; rr += 8)
    tile[rr][tx] = in[(size_t)(r0 + rr) * C + c0 + tx];
  __syncthreads();
  for (int cc = ty; cc < 32; cc += 8)
    out[(size_t)(c0 + cc) * R + r0 + tx] = __float2bfloat16(tile[tx][cc]);
}

// ---------------------------------------------------------------------------
// transpose V: [64 bh][1024 s][128 d] -> Vt [64 bh][128 d][1024 s] (bf16)
// ---------------------------------------------------------------------------
__global__ void transpose_v(const bf16* __restrict__ in, bf16* __restrict__ out) {
  __shared__ bf16 tile[32][33];
  int bh = blockIdx.z;
  const bf16* I = in + (size_t)bh * 1024 * 128;
  bf16* Ot = out + (size_t)bh * 1024 * 128;
  int c0 = blockIdx.x * 32, r0 = blockIdx.y * 32;  // c over d (128), r over s (1024)
  int tx = threadIdx.x & 31, ty = threadIdx.x >> 5;
  for (int rr = ty; rr < 32; rr += 8)
    tile[rr][tx] = I[(size_t)(r0 + rr) * 128 + c0 + tx];
  __syncthreads();
  for (int cc = ty; cc < 32; cc += 8)
    Ot[(size_t)(c0 + cc) * 1024 + r0 + tx] = tile[tx][cc];
}

// ---------------------------------------------------------------------------
// flow: expmap0 in place on Q and K ([B,H,S,HD] rows of 128). Q also * 1/sqrt(d)
// ---------------------------------------------------------------------------
__global__ __launch_bounds__(256)
void flow_kernel(bf16* __restrict__ Q, bf16* __restrict__ K) {
  const int lane = threadIdx.x & 63;
  const int row = blockIdx.x * 4 + (threadIdx.x >> 6);
  bf16* p = ((blockIdx.y == 0) ? Q : K) + (size_t)row * 128 + lane * 2;
  uint32_t u = *(const uint32_t*)p;
  float f0 = __uint_as_float(u << 16);
  float f1 = __uint_as_float(u & 0xffff0000u);
  float ss = f0 * f0 + f1 * f1;
#pragma unroll
  for (int off = 32; off; off >>= 1) ss += __shfl_xor(ss, off, 64);
  float n = fmaxf(sqrtf(ss), 1e-7f);
  float sc = tanhf(n) / n;
  if (blockIdx.y == 0) sc *= 0.08838834764831845f;  // 1/sqrt(128)
  __hip_bfloat162 o;
  o.x = __float2bfloat16(f0 * sc);
  o.y = __float2bfloat16(f1 * sc);
  *(__hip_bfloat162*)p = o;
}

// ---------------------------------------------------------------------------
// GEMM: C[M,N] = A[M,K](bf16,rm) @ Bt[N,K](bf16,rm)^T + bias
// 128x128 tile, BK=64, 4 waves of 4x4 16x16x32 MFMA tiles.
// MODE 0: write fp32 C row-major. MODE 1: scatter qkv -> Q/K/V bf16 [B,H,S,HD].
// ---------------------------------------------------------------------------
template <int MODE>
__global__ __launch_bounds__(256, 3)
void gemm_bt(const bf16* __restrict__ A, const bf16* __restrict__ Bt,
             const float* __restrict__ bias, float* __restrict__ Cf,
             bf16* __restrict__ Qo, bf16* __restrict__ Ko, bf16* __restrict__ Vo,
             int M, int N, int K) {
  __shared__ bf16 As[128 * 64];
  __shared__ bf16 Bs[128 * 64];
  const int t = threadIdx.x;
  const int w = t >> 6, lane = t & 63;
  const int lm = lane & 15, qd = lane >> 4;
  const int m0 = blockIdx.x * 128, n0 = blockIdx.y * 128;
  const int wm = (w & 1) * 64, wn = (w >> 1) * 64;

  const bf16* Ag = A + (size_t)m0 * K;
  const bf16* Bg = Bt + (size_t)n0 * K;

  f4v acc[4][4];
  f4v zero = {0.f, 0.f, 0.f, 0.f};
#pragma unroll
  for (int i = 0; i < 4; i++)
#pragma unroll
    for (int j = 0; j < 4; j++) acc[i][j] = zero;

  for (int k0 = 0; k0 < K; k0 += 64) {
#pragma unroll
    for (int c = 0; c < 4; c++) {
      int s = c * 256 + t;
      int r = s >> 3;
      int kc = (s & 7) ^ (r & 7);  // xor-swizzle: same 128B row, permuted 16B chunks
      gload16(Ag + (size_t)r * K + k0 + kc * 8, &As[s * 8]);
      gload16(Bg + (size_t)r * K + k0 + kc * 8, &Bs[s * 8]);
    }
    __syncthreads();
#pragma unroll
    for (int ks = 0; ks < 2; ks++) {
      b8 af[4], bfr[4];
#pragma unroll
      for (int tm = 0; tm < 4; tm++) {
        int row = wm + tm * 16 + lm;
        int ch = (ks * 4 + qd) ^ (row & 7);
        af[tm] = *(const b8*)&As[row * 64 + ch * 8];
      }
#pragma unroll
      for (int tn = 0; tn < 4; tn++) {
        int row = wn + tn * 16 + lm;
        int ch = (ks * 4 + qd) ^ (row & 7);
        bfr[tn] = *(const b8*)&Bs[row * 64 + ch * 8];
      }
#pragma unroll
      for (int tm = 0; tm < 4; tm++)
#pragma unroll
        for (int tn = 0; tn < 4; tn++)
          acc[tm][tn] = mfma_bf16(af[tm], bfr[tn], acc[tm][tn]);
    }
    __syncthreads();
  }

#pragma unroll
  for (int tm = 0; tm < 4; tm++) {
#pragma unroll
    for (int tn = 0; tn < 4; tn++) {
      int col = n0 + wn + tn * 16 + lm;
      float bv = bias[col];
      if (MODE == 0) {
#pragma unroll
        for (int r = 0; r < 4; r++) {
          int row = m0 + wm + tm * 16 + qd * 4 + r;  // C layout: row=(lane>>4)*4+reg
          Cf[(size_t)row * N + col] = acc[tm][tn][r] + bv;
        }
      } else {
        int part = col >> 10, h = (col >> 7) & 7, d = col & 127;
        bf16* dst = (part == 0) ? Qo : (part == 1) ? Ko : Vo;
#pragma unroll
        for (int r = 0; r < 4; r++) {
          int row = m0 + wm + tm * 16 + qd * 4 + r;
          int b = row >> 10, sIdx = row & 1023;
          dst[(((size_t)(b * 8 + h)) * 1024 + sIdx) * 128 + d] =
              __float2bfloat16(acc[tm][tn][r] + bv);
        }
      }
    }
  }
}

// ---------------------------------------------------------------------------
// Flash attention. grid (16 q-tiles, 64 bh), 256 thr = 4 waves x 16 q-rows.
// Q pre-flowed & pre-scaled; K pre-flowed; Vt is [bh][128 d][1024 s].
// O out fp32 [B,S,HID] (heads merged).
// ---------------------------------------------------------------------------
__global__ __launch_bounds__(256, 2)
void attn_kernel(const bf16* __restrict__ Qf, const bf16* __restrict__ Kf,
                 const bf16* __restrict__ Vt, float* __restrict__ O) {
  __shared__ bf16 Qs[64 * 128];
  __shared__ bf16 Ks[64 * 128];
  __shared__ bf16 Vs[128 * 64];
  __shared__ bf16 Ps[4][16 * 72];  // per-wave P, stride 72 (144B: 16B-aligned, 2-way banks)
  const int t = threadIdx.x, w = t >> 6, lane = t & 63;
  const int lm = lane & 15, qd = lane >> 4;
  const int bh = blockIdx.y, qt = blockIdx.x;
  const bf16* Qg = Qf + ((size_t)bh * 1024 + qt * 64) * 128;
  const bf16* Kg = Kf + (size_t)bh * 1024 * 128;
  const bf16* Vg = Vt + (size_t)bh * 128 * 1024;

#pragma unroll
  for (int c = 0; c < 4; c++) {
    int s = c * 256 + t;
    int r = s >> 4;
    int kc = (s & 15) ^ (r & 7);
    gload16(Qg + (size_t)r * 128 + kc * 8, &Qs[s * 8]);
  }
  __syncthreads();
  b8 qfr[4];
  const int qrow = w * 16 + lm;
#pragma unroll
  for (int ks = 0; ks < 4; ks++) {
    int ch = (ks * 4 + qd) ^ (qrow & 7);
    qfr[ks] = *(const b8*)&Qs[qrow * 128 + ch * 8];
  }

  f4v o[8];
  f4v zero = {0.f, 0.f, 0.f, 0.f};
#pragma unroll
  for (int i = 0; i < 8; i++) o[i] = zero;
  float mr[4] = {-1e30f, -1e30f, -1e30f, -1e30f};
  float lr[4] = {0.f, 0.f, 0.f, 0.f};

  for (int kt = 0; kt < 16; kt++) {
    __syncthreads();  // previous iter's Ks/Vs reads done
#pragma unroll
    for (int c = 0; c < 4; c++) {
      int s = c * 256 + t;
      int r = s >> 4;
      int kc = (s & 15) ^ (r & 7);
      gload16(Kg + (size_t)(kt * 64 + r) * 128 + kc * 8, &Ks[s * 8]);
      int rv = s >> 3;
      int kv = (s & 7) ^ (rv & 7);
      gload16(Vg + (size_t)rv * 1024 + kt * 64 + kv * 8, &Vs[s * 8]);
    }
    __syncthreads();

    // scores: D[q16][k16] per tn; A=Q(m=q,k=d), B=K^T (lane n = k-col)
    f4v sc[4];
#pragma unroll
    for (int tn = 0; tn < 4; tn++) {
      f4v c4 = zero;
      int krow = tn * 16 + lm;
#pragma unroll
      for (int ks = 0; ks < 4; ks++) {
        int ch = (ks * 4 + qd) ^ (krow & 7);
        b8 kfr = *(const b8*)&Ks[krow * 128 + ch * 8];
        c4 = mfma_bf16(qfr[ks], kfr, c4);
      }
      sc[tn] = c4;
    }

    // online softmax: row r lives in 16 lanes of this quad, reg r
    float rmax[4];
#pragma unroll
    for (int r = 0; r < 4; r++)
      rmax[r] = fmaxf(fmaxf(sc[0][r], sc[1][r]), fmaxf(sc[2][r], sc[3][r]));
#pragma unroll
    for (int r = 0; r < 4; r++)
#pragma unroll
      for (int offm = 1; offm < 16; offm <<= 1)
        rmax[r] = fmaxf(rmax[r], __shfl_xor(rmax[r], offm, 64));
    float al[4];
#pragma unroll
    for (int r = 0; r < 4; r++) {
      float mn = fmaxf(mr[r], rmax[r]);
      al[r] = __expf(mr[r] - mn);
      mr[r] = mn;
      lr[r] *= al[r];
    }
#pragma unroll
    for (int tn = 0; tn < 4; tn++)
#pragma unroll
      for (int r = 0; r < 4; r++) sc[tn][r] = __expf(sc[tn][r] - mr[r]);
#pragma unroll
    for (int r = 0; r < 4; r++) {
      float rs = sc[0][r] + sc[1][r] + sc[2][r] + sc[3][r];
#pragma unroll
      for (int offm = 1; offm < 16; offm <<= 1) rs += __shfl_xor(rs, offm, 64);
      lr[r] += rs;
    }
    // P: C-layout -> LDS -> A-layout (per-wave private buffer, no barrier)
#pragma unroll
    for (int tn = 0; tn < 4; tn++)
#pragma unroll
      for (int r = 0; r < 4; r++)
        Ps[w][(qd * 4 + r) * 72 + tn * 16 + lm] = __float2bfloat16(sc[tn][r]);
#pragma unroll
    for (int i = 0; i < 8; i++) {
      f4v t4 = o[i];
      t4[0] *= al[0]; t4[1] *= al[1]; t4[2] *= al[2]; t4[3] *= al[3];
      o[i] = t4;
    }
    b8 pa[2];
#pragma unroll
    for (int kv2 = 0; kv2 < 2; kv2++)
      pa[kv2] = *(const b8*)&Ps[w][lm * 72 + kv2 * 32 + qd * 8];
    // PV: A=P(m=q,k=s'), B=Vt (lane n = d)
#pragma unroll
    for (int tnd = 0; tnd < 8; tnd++) {
      int drow = tnd * 16 + lm;
#pragma unroll
      for (int kv2 = 0; kv2 < 2; kv2++) {
        int ch = (kv2 * 4 + qd) ^ (drow & 7);
        b8 vfr = *(const b8*)&Vs[drow * 64 + ch * 8];
        o[tnd] = mfma_bf16(pa[kv2], vfr, o[tnd]);
      }
    }
  }

  const int b = bh >> 3, h = bh & 7;
#pragma unroll
  for (int tnd = 0; tnd < 8; tnd++) {
    int d = tnd * 16 + lm;
#pragma unroll
    for (int r = 0; r < 4; r++) {
      int sIdx = qt * 64 + w * 16 + qd * 4 + r;
      O[((size_t)b * 1024 + sIdx) * 1024 + h * 128 + d] = o[tnd][r] / lr[r];
    }
  }
}

// ---------------------------------------------------------------------------
// update: m = o @ W_pinv + b_pinv (rank-8), upd = m @ W_attn[l] + b_attn[l],
// cur += upd, curb = bf16(cur). One block per (b,s) row.
// ---------------------------------------------------------------------------
__global__ __launch_bounds__(256)
void update_kernel(const float* __restrict__ O, const float* __restrict__ Wpinv,
                   const float* __restrict__ bpinv, const float* __restrict__ Wattn,
                   const float* __restrict__ battn, float* __restrict__ cur,
                   bf16* __restrict__ curb) {
  const int row = blockIdx.x;
  const int t = threadIdx.x, w = t >> 6, lane = t & 63;
  const float* orow = O + (size_t)row * 1024;
  float acc[8];
#pragma unroll
  for (int j = 0; j < 8; j++) acc[j] = 0.f;
  for (int h = t; h < 1024; h += 256) {
    float ov = orow[h];
#pragma unroll
    for (int j = 0; j < 8; j++) acc[j] += ov * Wpinv[h * 8 + j];
  }
#pragma unroll
  for (int j = 0; j < 8; j++)
#pragma unroll
    for (int off = 32; off; off >>= 1) acc[j] += __shfl_xor(acc[j], off, 64);
  __shared__ float sm[4][8];
  if (lane == 0) {
#pragma unroll
    for (int j = 0; j < 8; j++) sm[w][j] = acc[j];
  }
  __syncthreads();
  float mv[8];
#pragma unroll
  for (int j = 0; j < 8; j++)
    mv[j] = sm[0][j] + sm[1][j] + sm[2][j] + sm[3][j] + bpinv[j];
  for (int h = t; h < 1024; h += 256) {
    float u = battn[h];
#pragma unroll
    for (int j = 0; j < 8; j++) u += mv[j] * Wattn[j * 1024 + h];
    float c = cur[(size_t)row * 1024 + h] + u;
    cur[(size_t)row * 1024 + h] = c;
    curb[(size_t)row * 1024 + h] = __float2bfloat16(c);
  }
}

// ---------------------------------------------------------------------------
extern "C" void kernel_launch(void* const* d_in, const int* in_sizes, int n_in,
                              void* d_out, int out_size, void* d_ws, size_t ws_size,
                              hipStream_t stream) {
  const float* x      = (const float*)d_in[0];
  const float* W_qkv  = (const float*)d_in[1];
  const float* b_qkv  = (const float*)d_in[2];
  const float* W_pinv = (const float*)d_in[3];
  const float* b_pinv = (const float*)d_in[4];
  const float* W_attn = (const float*)d_in[5];
  const float* b_attn = (const float*)d_in[6];
  const float* W_out  = (const float*)d_in[7];
  const float* b_out  = (const float*)d_in[8];

  char* ws = (char*)d_ws;
  size_t off = 0;
  auto alloc = [&](size_t bytes) -> void* {
    void* p = ws + off;
    off += (bytes + 255) & ~(size_t)255;
    return p;
  };
  float* cur  = (float*)alloc((size_t)8192 * 1024 * 4);  // 32MB
  bf16* curb  = (bf16*)alloc((size_t)8192 * 1024 * 2);   // 16MB
  bf16* Wqkvt = (bf16*)alloc((size_t)3072 * 1024 * 2);   // 6MB  [3072][1024]
  bf16* Woutt = (bf16*)alloc((size_t)1024 * 1024 * 2);   // 2MB
  bf16* Q     = (bf16*)alloc((size_t)8192 * 1024 * 2);   // 16MB [B,H,S,HD]
  bf16* Kt    = (bf16*)alloc((size_t)8192 * 1024 * 2);
  bf16* V     = (bf16*)alloc((size_t)8192 * 1024 * 2);
  bf16* Vt    = (bf16*)alloc((size_t)8192 * 1024 * 2);   // [B,H,HD,S]
  float* O    = (float*)alloc((size_t)8192 * 1024 * 4);  // 32MB
  (void)ws_size; (void)in_sizes; (void)n_in; (void)out_size;

  prep_kernel<<<8192, 256, 0, stream>>>(x, cur, curb);
  transpose_cast<<<dim3(96, 32), 256, 0, stream>>>(W_qkv, Wqkvt, 1024, 3072);
  transpose_cast<<<dim3(32, 32), 256, 0, stream>>>(W_out, Woutt, 1024, 1024);

  for (int l = 0; l < 3; l++) {
    gemm_bt<1><<<dim3(64, 24), 256, 0, stream>>>(curb, Wqkvt, b_qkv, nullptr,
                                                 Q, Kt, V, 8192, 3072, 1024);
    flow_kernel<<<dim3(16384, 2), 256, 0, stream>>>(Q, Kt);
    transpose_v<<<dim3(4, 32, 64), 256, 0, stream>>>(V, Vt);
    attn_kernel<<<dim3(16, 64), 256, 0, stream>>>(Q, Kt, Vt, O);
    update_kernel<<<8192, 256, 0, stream>>>(O, W_pinv, b_pinv,
                                            W_attn + (size_t)l * 8 * 1024,
                                            b_attn + (size_t)l * 1024, cur, curb);
  }
  gemm_bt<0><<<dim3(64, 8), 256, 0, stream>>>(curb, Woutt, b_out, (float*)d_out,
                                              nullptr, nullptr, nullptr,
                                              8192, 1024, 1024);
}

// Round 2
// 735.657 us; speedup vs baseline: 1.0718x; 1.0718x over previous
//
#include <hip/hip_runtime.h>
#include <hip/hip_bf16.h>
#include <cstdint>

typedef __hip_bfloat16 bf16;
typedef __bf16 b8 __attribute__((ext_vector_type(8)));
typedef float f4v __attribute__((ext_vector_type(4)));

#define DEVI static __device__ __forceinline__

// async global->LDS, 16B per lane. LDS dest is wave-uniform base + lane*16.
DEVI void gload16(const void* g, void* l) {
  __builtin_amdgcn_global_load_lds(
      (const __attribute__((address_space(1))) void*)(uintptr_t)g,
      (__attribute__((address_space(3))) void*)(uint32_t)(uintptr_t)l,
      16, 0, 0);
}

DEVI f4v mfma_bf16(b8 a, b8 b, f4v c) {
  return __builtin_amdgcn_mfma_f32_16x16x32_bf16(a, b, c, 0, 0, 0);
}

// ---------------------------------------------------------------------------
// prep: x -> cur (fp32 copy) + curb (bf16)
// ---------------------------------------------------------------------------
__global__ void prep_kernel(const float* __restrict__ x, float* __restrict__ cur,
                            bf16* __restrict__ curb) {
  int i = (blockIdx.x * 256 + threadIdx.x) * 4;
  float4 v = *(const float4*)(x + i);
  *(float4*)(cur + i) = v;
  __hip_bfloat162 a, b;
  a.x = __float2bfloat16(v.x); a.y = __float2bfloat16(v.y);
  b.x = __float2bfloat16(v.z); b.y = __float2bfloat16(v.w);
  *(__hip_bfloat162*)(curb + i) = a;
  *(__hip_bfloat162*)(curb + i + 2) = b;
}

// ---------------------------------------------------------------------------
// transpose + cast fp32 [R][C] -> bf16 [C][R]   (weights, tiny)
// ---------------------------------------------------------------------------
__global__ void transpose_cast(const float* __restrict__ in, bf16* __restrict__ out,
                               int R, int C) {
  __shared__ float tile[32][33];
  int c0 = blockIdx.x * 32, r0 = blockIdx.y * 32;
  int tx = threadIdx.x & 31, ty = threadIdx.x >> 5;  // 32 x 8
  for (int rr = ty; rr < 32; rr += 8)
    tile[rr][tx] = in[(size_t)(r0 + rr) * C + c0 + tx];
  __syncthreads();
  for (int cc = ty; cc < 32; cc += 8)
    out[(size_t)(c0 + cc) * R + r0 + tx] = __float2bfloat16(tile[tx][cc]);
}

// ---------------------------------------------------------------------------
// flow: expmap0 in place on Q and K ([B,H,S,HD] rows of 128). Q also * 1/sqrt(d)
// ---------------------------------------------------------------------------
__global__ __launch_bounds__(256)
void flow_kernel(bf16* __restrict__ Q, bf16* __restrict__ K) {
  const int lane = threadIdx.x & 63;
  const int row = blockIdx.x * 4 + (threadIdx.x >> 6);
  bf16* p = ((blockIdx.y == 0) ? Q : K) + (size_t)row * 128 + lane * 2;
  uint32_t u = *(const uint32_t*)p;
  float f0 = __uint_as_float(u << 16);
  float f1 = __uint_as_float(u & 0xffff0000u);
  float ss = f0 * f0 + f1 * f1;
#pragma unroll
  for (int off = 32; off; off >>= 1) ss += __shfl_xor(ss, off, 64);
  float n = fmaxf(sqrtf(ss), 1e-7f);
  float sc = tanhf(n) / n;
  if (blockIdx.y == 0) sc *= 0.08838834764831845f;  // 1/sqrt(128)
  __hip_bfloat162 o;
  o.x = __float2bfloat16(f0 * sc);
  o.y = __float2bfloat16(f1 * sc);
  *(__hip_bfloat162*)p = o;
}

// ---------------------------------------------------------------------------
// GEMM: C[M,N] = A[M,K](bf16,rm) @ Bt[N,K](bf16,rm)^T + bias
// 128x128 tile, BK=64, 4 waves of 4x4 16x16x32 MFMA tiles.
// MODE 0: write fp32 C row-major.
// MODE 1: scatter qkv -> Q/K bf16 [B,H,S,HD]; V written TRANSPOSED to Vt[bh][d][s]
//         (the 4 acc regs are s-contiguous -> one 8B packed store).
// ---------------------------------------------------------------------------
template <int MODE>
__global__ __launch_bounds__(256, 3)
void gemm_bt(const bf16* __restrict__ A, const bf16* __restrict__ Bt,
             const float* __restrict__ bias, float* __restrict__ Cf,
             bf16* __restrict__ Qo, bf16* __restrict__ Ko, bf16* __restrict__ Vto,
             int M, int N, int K) {
  __shared__ bf16 As[128 * 64];
  __shared__ bf16 Bs[128 * 64];
  const int t = threadIdx.x;
  const int w = t >> 6, lane = t & 63;
  const int lm = lane & 15, qd = lane >> 4;
  const int m0 = blockIdx.x * 128, n0 = blockIdx.y * 128;
  const int wm = (w & 1) * 64, wn = (w >> 1) * 64;

  const bf16* Ag = A + (size_t)m0 * K;
  const bf16* Bg = Bt + (size_t)n0 * K;

  f4v acc[4][4];
  f4v zero = {0.f, 0.f, 0.f, 0.f};
#pragma unroll
  for (int i = 0; i < 4; i++)
#pragma unroll
    for (int j = 0; j < 4; j++) acc[i][j] = zero;

  for (int k0 = 0; k0 < K; k0 += 64) {
#pragma unroll
    for (int c = 0; c < 4; c++) {
      int s = c * 256 + t;
      int r = s >> 3;
      int kc = (s & 7) ^ (r & 7);  // xor-swizzle: same 128B row, permuted 16B chunks
      gload16(Ag + (size_t)r * K + k0 + kc * 8, &As[s * 8]);
      gload16(Bg + (size_t)r * K + k0 + kc * 8, &Bs[s * 8]);
    }
    __syncthreads();
#pragma unroll
    for (int ks = 0; ks < 2; ks++) {
      b8 af[4], bfr[4];
#pragma unroll
      for (int tm = 0; tm < 4; tm++) {
        int row = wm + tm * 16 + lm;
        int ch = (ks * 4 + qd) ^ (row & 7);
        af[tm] = *(const b8*)&As[row * 64 + ch * 8];
      }
#pragma unroll
      for (int tn = 0; tn < 4; tn++) {
        int row = wn + tn * 16 + lm;
        int ch = (ks * 4 + qd) ^ (row & 7);
        bfr[tn] = *(const b8*)&Bs[row * 64 + ch * 8];
      }
#pragma unroll
      for (int tm = 0; tm < 4; tm++)
#pragma unroll
        for (int tn = 0; tn < 4; tn++)
          acc[tm][tn] = mfma_bf16(af[tm], bfr[tn], acc[tm][tn]);
    }
    __syncthreads();
  }

#pragma unroll
  for (int tm = 0; tm < 4; tm++) {
#pragma unroll
    for (int tn = 0; tn < 4; tn++) {
      int col = n0 + wn + tn * 16 + lm;
      float bv = bias[col];
      if (MODE == 0) {
#pragma unroll
        for (int r = 0; r < 4; r++) {
          int row = m0 + wm + tm * 16 + qd * 4 + r;  // C layout: row=(lane>>4)*4+reg
          Cf[(size_t)row * N + col] = acc[tm][tn][r] + bv;
        }
      } else {
        int part = col >> 10, h = (col >> 7) & 7, d = col & 127;
        int row0 = m0 + wm + tm * 16 + qd * 4;
        int b = row0 >> 10, sIdx0 = row0 & 1023;
        if (part == 2) {
          bf16 vt[4];
#pragma unroll
          for (int r = 0; r < 4; r++) vt[r] = __float2bfloat16(acc[tm][tn][r] + bv);
          *(ushort4*)&Vto[((size_t)(b * 8 + h)) * 131072 + (size_t)d * 1024 + sIdx0] =
              *(ushort4*)vt;
        } else {
          bf16* dst = (part == 0) ? Qo : Ko;
#pragma unroll
          for (int r = 0; r < 4; r++)
            dst[(((size_t)(b * 8 + h)) * 1024 + sIdx0 + r) * 128 + d] =
                __float2bfloat16(acc[tm][tn][r] + bv);
        }
      }
    }
  }
}

// ---------------------------------------------------------------------------
// Flash attention, no-max softmax (scores bounded: |qf|,|kf|<1 on Poincare ball
// => |score| <= 1/sqrt(128) = 0.0884, exp(s) in [0.915,1.092] — m=0 is safe).
// grid (64 bh, 16 q-tiles): same-bh blocks stride 64 => same XCD => K/V L2-local.
// 256 thr = 4 waves x 16 q-rows. Q frags loaded global->reg (no Qs LDS).
// LDS exactly 40960 B => 4 blocks/CU.
// ---------------------------------------------------------------------------
__global__ __launch_bounds__(256, 4)
void attn_kernel(const bf16* __restrict__ Qf, const bf16* __restrict__ Kf,
                 const bf16* __restrict__ Vt, bf16* __restrict__ O) {
  __shared__ bf16 smem[20480];            // 40960 B total
  bf16* Ks = smem;                        // [64][128] chunk-swizzled
  bf16* Vs = smem + 8192;                 // [128][64] chunk-swizzled
  bf16* Ps = smem + 16384;                // [4 waves][16 q][64 s'] xor-swizzled
  const int t = threadIdx.x, w = t >> 6, lane = t & 63;
  const int lm = lane & 15, qd = lane >> 4;
  const int bh = blockIdx.x, qt = blockIdx.y;
  const bf16* Qg = Qf + ((size_t)bh * 1024 + qt * 64) * 128;
  const bf16* Kg = Kf + (size_t)bh * 1024 * 128;
  const bf16* Vg = Vt + (size_t)bh * 131072;
  bf16* Pw = Ps + w * 1024;

  // Q fragments straight from global (quad-contiguous 64B segments)
  b8 qfr[4];
  const int qrow = w * 16 + lm;
#pragma unroll
  for (int ks = 0; ks < 4; ks++)
    qfr[ks] = *(const b8*)(Qg + qrow * 128 + ks * 32 + qd * 8);

  f4v o[8];
  f4v zero = {0.f, 0.f, 0.f, 0.f};
#pragma unroll
  for (int i = 0; i < 8; i++) o[i] = zero;
  float lr[4] = {0.f, 0.f, 0.f, 0.f};

  for (int kt = 0; kt < 16; kt++) {
    __syncthreads();  // previous iter's Ks/Vs reads done
#pragma unroll
    for (int c = 0; c < 4; c++) {
      int s = c * 256 + t;
      int r = s >> 4;
      int kc = (s & 15) ^ (r & 7);
      gload16(Kg + (size_t)(kt * 64 + r) * 128 + kc * 8, &Ks[s * 8]);
      int rv = s >> 3;
      int kv = (s & 7) ^ (rv & 7);
      gload16(Vg + (size_t)rv * 1024 + kt * 64 + kv * 8, &Vs[s * 8]);
    }
    __syncthreads();

    // scores: A=Q(m=q,k=d), B=K (n=k-col)
    f4v sc[4];
#pragma unroll
    for (int tn = 0; tn < 4; tn++) {
      f4v c4 = zero;
      int krow = tn * 16 + lm;
#pragma unroll
      for (int ks = 0; ks < 4; ks++) {
        int ch = (ks * 4 + qd) ^ (krow & 7);
        b8 kfr = *(const b8*)&Ks[krow * 128 + ch * 8];
        c4 = mfma_bf16(qfr[ks], kfr, c4);
      }
      sc[tn] = c4;
    }

    // P = exp(s), no max subtraction needed (bounded scores)
#pragma unroll
    for (int tn = 0; tn < 4; tn++)
#pragma unroll
      for (int r = 0; r < 4; r++) sc[tn][r] = __expf(sc[tn][r]);

    // l += rowsum(P): reduce across the 16 lanes of each quad-row
#pragma unroll
    for (int r = 0; r < 4; r++) {
      float rs = (sc[0][r] + sc[1][r]) + (sc[2][r] + sc[3][r]);
#pragma unroll
      for (int offm = 1; offm < 16; offm <<= 1) rs += __shfl_xor(rs, offm, 64);
      lr[r] += rs;
    }

    // P: C-layout -> LDS (xor chunk swizzle, stride 64) -> A-layout; per-wave
#pragma unroll
    for (int tn = 0; tn < 4; tn++)
#pragma unroll
      for (int r = 0; r < 4; r++) {
        int q = qd * 4 + r;
        int ch = (tn * 2 + (lm >> 3)) ^ (q & 7);
        Pw[q * 64 + ch * 8 + (lm & 7)] = __float2bfloat16(sc[tn][r]);
      }
    b8 pa[2];
#pragma unroll
    for (int kv2 = 0; kv2 < 2; kv2++) {
      int ch = (kv2 * 4 + qd) ^ (lm & 7);
      pa[kv2] = *(const b8*)&Pw[lm * 64 + ch * 8];
    }
    // PV: A=P(m=q,k=s'), B=Vt (lane n = d)
#pragma unroll
    for (int tnd = 0; tnd < 8; tnd++) {
      int drow = tnd * 16 + lm;
#pragma unroll
      for (int kv2 = 0; kv2 < 2; kv2++) {
        int ch = (kv2 * 4 + qd) ^ (drow & 7);
        b8 vfr = *(const b8*)&Vs[drow * 64 + ch * 8];
        o[tnd] = mfma_bf16(pa[kv2], vfr, o[tnd]);
      }
    }
  }

  float rinv[4];
#pragma unroll
  for (int r = 0; r < 4; r++) rinv[r] = 1.0f / lr[r];
  const int b = bh >> 3, h = bh & 7;
#pragma unroll
  for (int tnd = 0; tnd < 8; tnd++) {
    int d = tnd * 16 + lm;
#pragma unroll
    for (int r = 0; r < 4; r++) {
      int sIdx = qt * 64 + w * 16 + qd * 4 + r;
      O[((size_t)b * 1024 + sIdx) * 1024 + h * 128 + d] =
          __float2bfloat16(o[tnd][r] * rinv[r]);
    }
  }
}

// ---------------------------------------------------------------------------
// update: m = o @ W_pinv + b_pinv (rank-8), upd = m @ W_attn[l] + b_attn[l],
// cur += upd, curb = bf16(cur). One block per (b,s) row; thread t owns h=4t..4t+3.
// ---------------------------------------------------------------------------
__global__ __launch_bounds__(256)
void update_kernel(const bf16* __restrict__ O, const float* __restrict__ Wpinv,
                   const float* __restrict__ bpinv, const float* __restrict__ Wattn,
                   const float* __restrict__ battn, float* __restrict__ cur,
                   bf16* __restrict__ curb) {
  const int row = blockIdx.x;
  const int t = threadIdx.x, w = t >> 6, lane = t & 63;
  const int h0 = t * 4;
  const bf16* orow = O + (size_t)row * 1024;

  bf16 ob[4];
  *(ushort4*)ob = *(const ushort4*)(orow + h0);
  float ov[4];
#pragma unroll
  for (int i = 0; i < 4; i++) ov[i] = __bfloat162float(ob[i]);

  float acc[8];
#pragma unroll
  for (int j = 0; j < 8; j++) acc[j] = 0.f;
#pragma unroll
  for (int i = 0; i < 4; i++) {
    float4 wa = *(const float4*)(Wpinv + (size_t)(h0 + i) * 8);
    float4 wb = *(const float4*)(Wpinv + (size_t)(h0 + i) * 8 + 4);
    acc[0] += ov[i] * wa.x; acc[1] += ov[i] * wa.y;
    acc[2] += ov[i] * wa.z; acc[3] += ov[i] * wa.w;
    acc[4] += ov[i] * wb.x; acc[5] += ov[i] * wb.y;
    acc[6] += ov[i] * wb.z; acc[7] += ov[i] * wb.w;
  }
#pragma unroll
  for (int j = 0; j < 8; j++)
#pragma unroll
    for (int off = 32; off; off >>= 1) acc[j] += __shfl_xor(acc[j], off, 64);
  __shared__ float sm[4][8];
  if (lane == 0) {
#pragma unroll
    for (int j = 0; j < 8; j++) sm[w][j] = acc[j];
  }
  __syncthreads();
  float mv[8];
#pragma unroll
  for (int j = 0; j < 8; j++)
    mv[j] = sm[0][j] + sm[1][j] + sm[2][j] + sm[3][j] + bpinv[j];

  float u[4];
#pragma unroll
  for (int i = 0; i < 4; i++) u[i] = battn[h0 + i];
#pragma unroll
  for (int j = 0; j < 8; j++) {
    float4 wv = *(const float4*)(Wattn + (size_t)j * 1024 + h0);
    u[0] += mv[j] * wv.x; u[1] += mv[j] * wv.y;
    u[2] += mv[j] * wv.z; u[3] += mv[j] * wv.w;
  }
  float4 c4 = *(float4*)(cur + (size_t)row * 1024 + h0);
  c4.x += u[0]; c4.y += u[1]; c4.z += u[2]; c4.w += u[3];
  *(float4*)(cur + (size_t)row * 1024 + h0) = c4;
  bf16 cb[4];
  cb[0] = __float2bfloat16(c4.x); cb[1] = __float2bfloat16(c4.y);
  cb[2] = __float2bfloat16(c4.z); cb[3] = __float2bfloat16(c4.w);
  *(ushort4*)(curb + (size_t)row * 1024 + h0) = *(ushort4*)cb;
}

// ---------------------------------------------------------------------------
extern "C" void kernel_launch(void* const* d_in, const int* in_sizes, int n_in,
                              void* d_out, int out_size, void* d_ws, size_t ws_size,
                              hipStream_t stream) {
  const float* x      = (const float*)d_in[0];
  const float* W_qkv  = (const float*)d_in[1];
  const float* b_qkv  = (const float*)d_in[2];
  const float* W_pinv = (const float*)d_in[3];
  const float* b_pinv = (const float*)d_in[4];
  const float* W_attn = (const float*)d_in[5];
  const float* b_attn = (const float*)d_in[6];
  const float* W_out  = (const float*)d_in[7];
  const float* b_out  = (const float*)d_in[8];

  char* ws = (char*)d_ws;
  size_t off = 0;
  auto alloc = [&](size_t bytes) -> void* {
    void* p = ws + off;
    off += (bytes + 255) & ~(size_t)255;
    return p;
  };
  float* cur  = (float*)alloc((size_t)8192 * 1024 * 4);  // 32MB
  bf16* curb  = (bf16*)alloc((size_t)8192 * 1024 * 2);   // 16MB
  bf16* Wqkvt = (bf16*)alloc((size_t)3072 * 1024 * 2);   // 6MB  [3072][1024]
  bf16* Woutt = (bf16*)alloc((size_t)1024 * 1024 * 2);   // 2MB
  bf16* Q     = (bf16*)alloc((size_t)8192 * 1024 * 2);   // 16MB [B,H,S,HD]
  bf16* Kt    = (bf16*)alloc((size_t)8192 * 1024 * 2);   // 16MB [B,H,S,HD]
  bf16* Vt    = (bf16*)alloc((size_t)8192 * 1024 * 2);   // 16MB [B,H,HD,S]
  bf16* O     = (bf16*)alloc((size_t)8192 * 1024 * 2);   // 16MB
  (void)ws_size; (void)in_sizes; (void)n_in; (void)out_size;

  prep_kernel<<<8192, 256, 0, stream>>>(x, cur, curb);
  transpose_cast<<<dim3(96, 32), 256, 0, stream>>>(W_qkv, Wqkvt, 1024, 3072);
  transpose_cast<<<dim3(32, 32), 256, 0, stream>>>(W_out, Woutt, 1024, 1024);

  for (int l = 0; l < 3; l++) {
    gemm_bt<1><<<dim3(64, 24), 256, 0, stream>>>(curb, Wqkvt, b_qkv, nullptr,
                                                 Q, Kt, Vt, 8192, 3072, 1024);
    flow_kernel<<<dim3(16384, 2), 256, 0, stream>>>(Q, Kt);
    attn_kernel<<<dim3(64, 16), 256, 0, stream>>>(Q, Kt, Vt, O);
    update_kernel<<<8192, 256, 0, stream>>>(O, W_pinv, b_pinv,
                                            W_attn + (size_t)l * 8 * 1024,
                                            b_attn + (size_t)l * 1024, cur, curb);
  }
  gemm_bt<0><<<dim3(64, 8), 256, 0, stream>>>(curb, Woutt, b_out, (float*)d_out,
                                              nullptr, nullptr, nullptr,
                                              8192, 1024, 1024);
}

// Round 3
// 587.752 us; speedup vs baseline: 1.3415x; 1.2516x over previous
//
#include <hip/hip_runtime.h>
#include <hip/hip_bf16.h>
#include <cstdint>

typedef __hip_bfloat16 bf16;
typedef __bf16 b8 __attribute__((ext_vector_type(8)));
typedef float f4v __attribute__((ext_vector_type(4)));
typedef short s8v __attribute__((ext_vector_type(8)));

#define DEVI static __device__ __forceinline__

// async global->LDS, 16B per lane. LDS dest is wave-uniform base + lane*16.
DEVI void gload16(const void* g, void* l) {
  __builtin_amdgcn_global_load_lds(
      (const __attribute__((address_space(1))) void*)(uintptr_t)g,
      (__attribute__((address_space(3))) void*)(uint32_t)(uintptr_t)l,
      16, 0, 0);
}

DEVI f4v mfma_bf16(b8 a, b8 b, f4v c) {
  return __builtin_amdgcn_mfma_f32_16x16x32_bf16(a, b, c, 0, 0, 0);
}

// ---------------------------------------------------------------------------
// prep: x -> cur (fp32 copy) + curb (bf16)
// ---------------------------------------------------------------------------
__global__ void prep_kernel(const float* __restrict__ x, float* __restrict__ cur,
                            bf16* __restrict__ curb) {
  int i = (blockIdx.x * 256 + threadIdx.x) * 4;
  float4 v = *(const float4*)(x + i);
  *(float4*)(cur + i) = v;
  __hip_bfloat162 a, b;
  a.x = __float2bfloat16(v.x); a.y = __float2bfloat16(v.y);
  b.x = __float2bfloat16(v.z); b.y = __float2bfloat16(v.w);
  *(__hip_bfloat162*)(curb + i) = a;
  *(__hip_bfloat162*)(curb + i + 2) = b;
}

// ---------------------------------------------------------------------------
// transpose + cast fp32 [R][C] -> bf16 [C][R]   (weights, tiny)
// ---------------------------------------------------------------------------
__global__ void transpose_cast(const float* __restrict__ in, bf16* __restrict__ out,
                               int R, int C) {
  __shared__ float tile[32][33];
  int c0 = blockIdx.x * 32, r0 = blockIdx.y * 32;
  int tx = threadIdx.x & 31, ty = threadIdx.x >> 5;  // 32 x 8
  for (int rr = ty; rr < 32; rr += 8)
    tile[rr][tx] = in[(size_t)(r0 + rr) * C + c0 + tx];
  __syncthreads();
  for (int cc = ty; cc < 32; cc += 8)
    out[(size_t)(c0 + cc) * R + r0 + tx] = __float2bfloat16(tile[tx][cc]);
}

// ---------------------------------------------------------------------------
// GEMM: C[M,N] = A[M,K](bf16,rm) @ Bt[N,K](bf16,rm)^T + bias
// 128x128 tile, BK=64, 4 waves of 4x4 16x16x32 MFMA tiles.
// MODE 0: write fp32 C row-major.
// MODE 1: n-tile (128-wide, aligned) = one (part,head) full d-range.
//   part 0/1 (Q/K): fused expmap0 (row-norm over the block's 128 cols via
//   shfl + 1KB LDS cross-wave combine), Q also * 1/sqrt(d). part 2 (V):
//   store transposed to Vt[bh][d][s] (4 acc regs are s-contiguous -> ushort4).
// ---------------------------------------------------------------------------
template <int MODE>
__global__ __launch_bounds__(256, 3)
void gemm_bt(const bf16* __restrict__ A, const bf16* __restrict__ Bt,
             const float* __restrict__ bias, float* __restrict__ Cf,
             bf16* __restrict__ Qo, bf16* __restrict__ Ko, bf16* __restrict__ Vto,
             int M, int N, int K) {
  __shared__ bf16 As[128 * 64];
  __shared__ bf16 Bs[128 * 64];
  __shared__ float red[2][128];
  const int t = threadIdx.x;
  const int w = t >> 6, lane = t & 63;
  const int lm = lane & 15, qd = lane >> 4;
  const int m0 = blockIdx.x * 128, n0 = blockIdx.y * 128;
  const int wm = (w & 1) * 64, wn = (w >> 1) * 64;

  const bf16* Ag = A + (size_t)m0 * K;
  const bf16* Bg = Bt + (size_t)n0 * K;

  f4v acc[4][4];
  f4v zero = {0.f, 0.f, 0.f, 0.f};
#pragma unroll
  for (int i = 0; i < 4; i++)
#pragma unroll
    for (int j = 0; j < 4; j++) acc[i][j] = zero;

  for (int k0 = 0; k0 < K; k0 += 64) {
#pragma unroll
    for (int c = 0; c < 4; c++) {
      int s = c * 256 + t;
      int r = s >> 3;
      int kc = (s & 7) ^ (r & 7);  // xor-swizzle: same 128B row, permuted 16B chunks
      gload16(Ag + (size_t)r * K + k0 + kc * 8, &As[s * 8]);
      gload16(Bg + (size_t)r * K + k0 + kc * 8, &Bs[s * 8]);
    }
    __syncthreads();
#pragma unroll
    for (int ks = 0; ks < 2; ks++) {
      b8 af[4], bfr[4];
#pragma unroll
      for (int tm = 0; tm < 4; tm++) {
        int row = wm + tm * 16 + lm;
        int ch = (ks * 4 + qd) ^ (row & 7);
        af[tm] = *(const b8*)&As[row * 64 + ch * 8];
      }
#pragma unroll
      for (int tn = 0; tn < 4; tn++) {
        int row = wn + tn * 16 + lm;
        int ch = (ks * 4 + qd) ^ (row & 7);
        bfr[tn] = *(const b8*)&Bs[row * 64 + ch * 8];
      }
#pragma unroll
      for (int tm = 0; tm < 4; tm++)
#pragma unroll
        for (int tn = 0; tn < 4; tn++)
          acc[tm][tn] = mfma_bf16(af[tm], bfr[tn], acc[tm][tn]);
    }
    __syncthreads();
  }

  if (MODE == 0) {
#pragma unroll
    for (int tm = 0; tm < 4; tm++)
#pragma unroll
      for (int tn = 0; tn < 4; tn++) {
        int col = n0 + wn + tn * 16 + lm;
        float bv = bias[col];
#pragma unroll
        for (int r = 0; r < 4; r++) {
          int row = m0 + wm + tm * 16 + qd * 4 + r;  // C layout: row=(lane>>4)*4+reg
          Cf[(size_t)row * N + col] = acc[tm][tn][r] + bv;
        }
      }
  } else {
    const int part = n0 >> 10;          // block-uniform: 0=Q, 1=K, 2=V
    const int hh = (n0 >> 7) & 7;
    if (part == 2) {
#pragma unroll
      for (int tm = 0; tm < 4; tm++)
#pragma unroll
        for (int tn = 0; tn < 4; tn++) {
          int d = wn + tn * 16 + lm;
          float bv = bias[n0 + d];
          int row0 = m0 + wm + tm * 16 + qd * 4;
          int b = row0 >> 10, s0 = row0 & 1023;
          bf16 vt[4];
#pragma unroll
          for (int r = 0; r < 4; r++) vt[r] = __float2bfloat16(acc[tm][tn][r] + bv);
          *(ushort4*)&Vto[((size_t)(b * 8 + hh)) * 131072 + (size_t)d * 1024 + s0] =
              *(ushort4*)vt;
        }
    } else {
      float bvs[4];
#pragma unroll
      for (int tn = 0; tn < 4; tn++) bvs[tn] = bias[n0 + wn + tn * 16 + lm];
      float ss[4][4];
#pragma unroll
      for (int tm = 0; tm < 4; tm++)
#pragma unroll
        for (int r = 0; r < 4; r++) {
          float s = 0.f;
#pragma unroll
          for (int tn = 0; tn < 4; tn++) {
            float v = acc[tm][tn][r] + bvs[tn];
            s += v * v;
          }
#pragma unroll
          for (int off = 1; off < 16; off <<= 1) s += __shfl_xor(s, off, 64);
          ss[tm][r] = s;
        }
      if (lm == 0) {
#pragma unroll
        for (int tm = 0; tm < 4; tm++)
#pragma unroll
          for (int r = 0; r < 4; r++)
            red[w >> 1][wm + tm * 16 + qd * 4 + r] = ss[tm][r];
      }
      __syncthreads();
      const float qsc = (part == 0) ? 0.08838834764831845f : 1.0f;  // 1/sqrt(128)
      float scr[4][4];
#pragma unroll
      for (int tm = 0; tm < 4; tm++)
#pragma unroll
        for (int r = 0; r < 4; r++) {
          int row = wm + tm * 16 + qd * 4 + r;
          float tot = red[0][row] + red[1][row];
          float nrm = fmaxf(sqrtf(tot), 1e-7f);
          scr[tm][r] = tanhf(nrm) / nrm * qsc;
        }
      bf16* dst = (part == 0) ? Qo : Ko;
#pragma unroll
      for (int tm = 0; tm < 4; tm++)
#pragma unroll
        for (int tn = 0; tn < 4; tn++) {
          int d = wn + tn * 16 + lm;
          int row0 = m0 + wm + tm * 16 + qd * 4;
          int b = row0 >> 10, s0 = row0 & 1023;
#pragma unroll
          for (int r = 0; r < 4; r++)
            dst[(((size_t)(b * 8 + hh)) * 1024 + s0 + r) * 128 + d] =
                __float2bfloat16((acc[tm][tn][r] + bvs[tn]) * scr[tm][r]);
        }
    }
  }
}

// ---------------------------------------------------------------------------
// Flash attention, no-max softmax (|qf|,|kf|<1 on Poincare ball => |score| <=
// 1/sqrt(128); exp in [0.915,1.092] — m=0 safe; rowsum l via MFMA against a
// constant all-ones B fragment -> same C-layout as o, no shfl).
// grid (64 bh, 8 qt): same-bh blocks stride 64 => same XCD => K/V L2-local.
// 256 thr = 4 waves x 32 q-rows (2 m-tiles) => K/V LDS reads amortized 2x.
// LDS 48 KB, 512 blocks = exactly 2/CU.
// ---------------------------------------------------------------------------
__global__ __launch_bounds__(256, 2)
void attn_kernel(const bf16* __restrict__ Qf, const bf16* __restrict__ Kf,
                 const bf16* __restrict__ Vt, bf16* __restrict__ O) {
  __shared__ bf16 smem[24576];            // 49152 B
  bf16* Ks = smem;                        // [64 s'][128 d] chunk-swizzled
  bf16* Vs = smem + 8192;                 // [128 d][64 s'] chunk-swizzled
  bf16* Ps = smem + 16384;                // [4 waves][32 q][64 s'] perm-swizzled
  const int t = threadIdx.x, w = t >> 6, lane = t & 63;
  const int lm = lane & 15, qd = lane >> 4;
  const int bh = blockIdx.x, qt = blockIdx.y;
  const bf16* Qg = Qf + ((size_t)bh * 1024 + qt * 128) * 128;
  const bf16* Kg = Kf + (size_t)bh * 131072;
  const bf16* Vg = Vt + (size_t)bh * 131072;
  bf16* Pw = Ps + w * 2048;

  // Q fragments straight from global (quad-contiguous 64B segments)
  b8 qfr[2][4];
#pragma unroll
  for (int mt = 0; mt < 2; mt++)
#pragma unroll
    for (int ks = 0; ks < 4; ks++)
      qfr[mt][ks] =
          *(const b8*)(Qg + (size_t)(w * 32 + mt * 16 + lm) * 128 + ks * 32 + qd * 8);

  f4v o[2][8];
  f4v lacc[2];
  f4v zero = {0.f, 0.f, 0.f, 0.f};
#pragma unroll
  for (int mt = 0; mt < 2; mt++) {
    lacc[mt] = zero;
#pragma unroll
    for (int i = 0; i < 8; i++) o[mt][i] = zero;
  }
  union { s8v s; b8 b; } uo;
#pragma unroll
  for (int i = 0; i < 8; i++) uo.s[i] = 0x3F80;  // bf16 1.0
  const b8 ones = uo.b;

  for (int kt = 0; kt < 16; kt++) {
    __syncthreads();  // previous iter's Ks/Vs/Ps reads done
#pragma unroll
    for (int c = 0; c < 4; c++) {
      int s = c * 256 + t;
      int r = s >> 4;
      int kc = (s & 15) ^ (r & 7);
      gload16(Kg + (size_t)(kt * 64 + r) * 128 + kc * 8, &Ks[s * 8]);
      int rv = s >> 3;
      int kv = (s & 7) ^ (rv & 7);
      gload16(Vg + (size_t)rv * 1024 + kt * 64 + kv * 8, &Vs[s * 8]);
    }
    __syncthreads();

#pragma unroll
    for (int mt = 0; mt < 2; mt++) {
      // scores: A=Q(m=q,k=d), B=K (n=k-col)
      f4v sc[4];
#pragma unroll
      for (int tn = 0; tn < 4; tn++) {
        f4v c4 = zero;
        int krow = tn * 16 + lm;
#pragma unroll
        for (int ks = 0; ks < 4; ks++) {
          int ch = (ks * 4 + qd) ^ (krow & 7);
          b8 kfr = *(const b8*)&Ks[krow * 128 + ch * 8];
          c4 = mfma_bf16(qfr[mt][ks], kfr, c4);
        }
        sc[tn] = c4;
      }
      // P = exp(s) -> LDS (perm swizzle (q>>1)&7: 8 distinct chunks across the
      // 4 quads -> 2 lanes/bank on writes, balanced b128 reads)
#pragma unroll
      for (int tn = 0; tn < 4; tn++)
#pragma unroll
        for (int r = 0; r < 4; r++) {
          int qi = mt * 16 + qd * 4 + r;
          int ch = (tn * 2 + (lm >> 3)) ^ ((qi >> 1) & 7);
          Pw[qi * 64 + ch * 8 + (lm & 7)] = __float2bfloat16(__expf(sc[tn][r]));
        }
    }

    b8 pa[2][2];
#pragma unroll
    for (int mt = 0; mt < 2; mt++)
#pragma unroll
      for (int kv2 = 0; kv2 < 2; kv2++) {
        int qi = mt * 16 + lm;
        int ch = (kv2 * 4 + qd) ^ ((lm >> 1) & 7);
        pa[mt][kv2] = *(const b8*)&Pw[qi * 64 + ch * 8];
      }
    // l += rowsum(P) via MFMA with B=ones (C-layout matches o)
#pragma unroll
    for (int mt = 0; mt < 2; mt++)
#pragma unroll
      for (int kv2 = 0; kv2 < 2; kv2++)
        lacc[mt] = mfma_bf16(pa[mt][kv2], ones, lacc[mt]);
    // PV: A=P(m=q,k=s'), B=Vt (lane n = d); V frags shared across both m-tiles
#pragma unroll
    for (int tnd = 0; tnd < 8; tnd++) {
      int drow = tnd * 16 + lm;
#pragma unroll
      for (int kv2 = 0; kv2 < 2; kv2++) {
        int ch = (kv2 * 4 + qd) ^ (drow & 7);
        b8 vfr = *(const b8*)&Vs[drow * 64 + ch * 8];
#pragma unroll
        for (int mt = 0; mt < 2; mt++)
          o[mt][tnd] = mfma_bf16(pa[mt][kv2], vfr, o[mt][tnd]);
      }
    }
  }

  const int b = bh >> 3, h = bh & 7;
#pragma unroll
  for (int mt = 0; mt < 2; mt++) {
    float rinv[4];
#pragma unroll
    for (int r = 0; r < 4; r++) rinv[r] = 1.0f / lacc[mt][r];
#pragma unroll
    for (int tnd = 0; tnd < 8; tnd++) {
      int d = tnd * 16 + lm;
#pragma unroll
      for (int r = 0; r < 4; r++) {
        int sIdx = qt * 128 + w * 32 + mt * 16 + qd * 4 + r;
        O[((size_t)b * 1024 + sIdx) * 1024 + h * 128 + d] =
            __float2bfloat16(o[mt][tnd][r] * rinv[r]);
      }
    }
  }
}

// ---------------------------------------------------------------------------
// update: m = o @ W_pinv + b_pinv (rank-8), upd = m @ W_attn[l] + b_attn[l],
// cur += upd, curb = bf16(cur). One block per (b,s) row; thread t owns h=4t..4t+3.
// ---------------------------------------------------------------------------
__global__ __launch_bounds__(256)
void update_kernel(const bf16* __restrict__ O, const float* __restrict__ Wpinv,
                   const float* __restrict__ bpinv, const float* __restrict__ Wattn,
                   const float* __restrict__ battn, float* __restrict__ cur,
                   bf16* __restrict__ curb) {
  const int row = blockIdx.x;
  const int t = threadIdx.x, w = t >> 6, lane = t & 63;
  const int h0 = t * 4;
  const bf16* orow = O + (size_t)row * 1024;

  bf16 ob[4];
  *(ushort4*)ob = *(const ushort4*)(orow + h0);
  float ov[4];
#pragma unroll
  for (int i = 0; i < 4; i++) ov[i] = __bfloat162float(ob[i]);

  float acc[8];
#pragma unroll
  for (int j = 0; j < 8; j++) acc[j] = 0.f;
#pragma unroll
  for (int i = 0; i < 4; i++) {
    float4 wa = *(const float4*)(Wpinv + (size_t)(h0 + i) * 8);
    float4 wb = *(const float4*)(Wpinv + (size_t)(h0 + i) * 8 + 4);
    acc[0] += ov[i] * wa.x; acc[1] += ov[i] * wa.y;
    acc[2] += ov[i] * wa.z; acc[3] += ov[i] * wa.w;
    acc[4] += ov[i] * wb.x; acc[5] += ov[i] * wb.y;
    acc[6] += ov[i] * wb.z; acc[7] += ov[i] * wb.w;
  }
#pragma unroll
  for (int j = 0; j < 8; j++)
#pragma unroll
    for (int off = 32; off; off >>= 1) acc[j] += __shfl_xor(acc[j], off, 64);
  __shared__ float sm[4][8];
  if (lane == 0) {
#pragma unroll
    for (int j = 0; j < 8; j++) sm[w][j] = acc[j];
  }
  __syncthreads();
  float mv[8];
#pragma unroll
  for (int j = 0; j < 8; j++)
    mv[j] = sm[0][j] + sm[1][j] + sm[2][j] + sm[3][j] + bpinv[j];

  float u[4];
#pragma unroll
  for (int i = 0; i < 4; i++) u[i] = battn[h0 + i];
#pragma unroll
  for (int j = 0; j < 8; j++) {
    float4 wv = *(const float4*)(Wattn + (size_t)j * 1024 + h0);
    u[0] += mv[j] * wv.x; u[1] += mv[j] * wv.y;
    u[2] += mv[j] * wv.z; u[3] += mv[j] * wv.w;
  }
  float4 c4 = *(float4*)(cur + (size_t)row * 1024 + h0);
  c4.x += u[0]; c4.y += u[1]; c4.z += u[2]; c4.w += u[3];
  *(float4*)(cur + (size_t)row * 1024 + h0) = c4;
  bf16 cb[4];
  cb[0] = __float2bfloat16(c4.x); cb[1] = __float2bfloat16(c4.y);
  cb[2] = __float2bfloat16(c4.z); cb[3] = __float2bfloat16(c4.w);
  *(ushort4*)(curb + (size_t)row * 1024 + h0) = *(ushort4*)cb;
}

// ---------------------------------------------------------------------------
extern "C" void kernel_launch(void* const* d_in, const int* in_sizes, int n_in,
                              void* d_out, int out_size, void* d_ws, size_t ws_size,
                              hipStream_t stream) {
  const float* x      = (const float*)d_in[0];
  const float* W_qkv  = (const float*)d_in[1];
  const float* b_qkv  = (const float*)d_in[2];
  const float* W_pinv = (const float*)d_in[3];
  const float* b_pinv = (const float*)d_in[4];
  const float* W_attn = (const float*)d_in[5];
  const float* b_attn = (const float*)d_in[6];
  const float* W_out  = (const float*)d_in[7];
  const float* b_out  = (const float*)d_in[8];

  char* ws = (char*)d_ws;
  size_t off = 0;
  auto alloc = [&](size_t bytes) -> void* {
    void* p = ws + off;
    off += (bytes + 255) & ~(size_t)255;
    return p;
  };
  float* cur  = (float*)alloc((size_t)8192 * 1024 * 4);  // 32MB
  bf16* curb  = (bf16*)alloc((size_t)8192 * 1024 * 2);   // 16MB
  bf16* Wqkvt = (bf16*)alloc((size_t)3072 * 1024 * 2);   // 6MB  [3072][1024]
  bf16* Woutt = (bf16*)alloc((size_t)1024 * 1024 * 2);   // 2MB
  bf16* Q     = (bf16*)alloc((size_t)8192 * 1024 * 2);   // 16MB [B,H,S,HD] (flowed)
  bf16* Kt    = (bf16*)alloc((size_t)8192 * 1024 * 2);   // 16MB [B,H,S,HD] (flowed)
  bf16* Vt    = (bf16*)alloc((size_t)8192 * 1024 * 2);   // 16MB [B,H,HD,S]
  bf16* O     = (bf16*)alloc((size_t)8192 * 1024 * 2);   // 16MB
  (void)ws_size; (void)in_sizes; (void)n_in; (void)out_size;

  prep_kernel<<<8192, 256, 0, stream>>>(x, cur, curb);
  transpose_cast<<<dim3(96, 32), 256, 0, stream>>>(W_qkv, Wqkvt, 1024, 3072);
  transpose_cast<<<dim3(32, 32), 256, 0, stream>>>(W_out, Woutt, 1024, 1024);

  for (int l = 0; l < 3; l++) {
    gemm_bt<1><<<dim3(64, 24), 256, 0, stream>>>(curb, Wqkvt, b_qkv, nullptr,
                                                 Q, Kt, Vt, 8192, 3072, 1024);
    attn_kernel<<<dim3(64, 8), 256, 0, stream>>>(Q, Kt, Vt, O);
    update_kernel<<<8192, 256, 0, stream>>>(O, W_pinv, b_pinv,
                                            W_attn + (size_t)l * 8 * 1024,
                                            b_attn + (size_t)l * 1024, cur, curb);
  }
  gemm_bt<0><<<dim3(64, 8), 256, 0, stream>>>(curb, Woutt, b_out, (float*)d_out,
                                              nullptr, nullptr, nullptr,
                                              8192, 1024, 1024);
}

// Round 4
// 547.928 us; speedup vs baseline: 1.4390x; 1.0727x over previous
//
#include <hip/hip_runtime.h>
#include <hip/hip_bf16.h>
#include <hip/hip_fp8.h>
#include <cstdint>

typedef __hip_bfloat16 bf16;
typedef __bf16 b8 __attribute__((ext_vector_type(8)));
typedef float f4v __attribute__((ext_vector_type(4)));
typedef short s8v __attribute__((ext_vector_type(8)));
typedef int i8v __attribute__((ext_vector_type(8)));

#define DEVI static __device__ __forceinline__

// async global->LDS, 16B per lane. LDS dest is wave-uniform base + lane*16.
DEVI void gload16(const void* g, void* l) {
  __builtin_amdgcn_global_load_lds(
      (const __attribute__((address_space(1))) void*)(uintptr_t)g,
      (__attribute__((address_space(3))) void*)(uint32_t)(uintptr_t)l,
      16, 0, 0);
}

DEVI f4v mfma_bf16(b8 a, b8 b, f4v c) {
  return __builtin_amdgcn_mfma_f32_16x16x32_bf16(a, b, c, 0, 0, 0);
}

// MX-scaled fp8 (OCP e4m3), K=128, unit scales (E8M0 127 = 2^0 in every byte).
DEVI f4v mfma_fp8(i8v a, i8v b, f4v c) {
  return __builtin_amdgcn_mfma_scale_f32_16x16x128_f8f6f4(
      a, b, c, 0, 0, 0, 0x7F7F7F7F, 0, 0x7F7F7F7F);
}

DEVI uint8_t to_fp8(float f) {
  __hip_fp8_e4m3 v(f);
  return v.__x;
}

// ---------------------------------------------------------------------------
// prep: x -> cur (fp32) + curb (bf16) + curf8 (fp8 e4m3)
// ---------------------------------------------------------------------------
__global__ void prep_kernel(const float* __restrict__ x, float* __restrict__ cur,
                            bf16* __restrict__ curb, uint8_t* __restrict__ curf8) {
  int i = (blockIdx.x * 256 + threadIdx.x) * 4;
  float4 v = *(const float4*)(x + i);
  *(float4*)(cur + i) = v;
  __hip_bfloat162 a, b;
  a.x = __float2bfloat16(v.x); a.y = __float2bfloat16(v.y);
  b.x = __float2bfloat16(v.z); b.y = __float2bfloat16(v.w);
  *(__hip_bfloat162*)(curb + i) = a;
  *(__hip_bfloat162*)(curb + i + 2) = b;
  uint32_t p = (uint32_t)to_fp8(v.x) | ((uint32_t)to_fp8(v.y) << 8) |
               ((uint32_t)to_fp8(v.z) << 16) | ((uint32_t)to_fp8(v.w) << 24);
  *(uint32_t*)(curf8 + i) = p;
}

// ---------------------------------------------------------------------------
// transpose + cast fp32 [R][C] -> bf16 [C][R]   (weights, tiny)
// ---------------------------------------------------------------------------
__global__ void transpose_cast(const float* __restrict__ in, bf16* __restrict__ out,
                               int R, int C) {
  __shared__ float tile[32][33];
  int c0 = blockIdx.x * 32, r0 = blockIdx.y * 32;
  int tx = threadIdx.x & 31, ty = threadIdx.x >> 5;  // 32 x 8
  for (int rr = ty; rr < 32; rr += 8)
    tile[rr][tx] = in[(size_t)(r0 + rr) * C + c0 + tx];
  __syncthreads();
  for (int cc = ty; cc < 32; cc += 8)
    out[(size_t)(c0 + cc) * R + r0 + tx] = __float2bfloat16(tile[tx][cc]);
}

// transpose + cast fp32 [R][C] -> fp8 [C][R]
__global__ void transpose_cast_fp8(const float* __restrict__ in,
                                   uint8_t* __restrict__ out, int R, int C) {
  __shared__ float tile[32][33];
  int c0 = blockIdx.x * 32, r0 = blockIdx.y * 32;
  int tx = threadIdx.x & 31, ty = threadIdx.x >> 5;
  for (int rr = ty; rr < 32; rr += 8)
    tile[rr][tx] = in[(size_t)(r0 + rr) * C + c0 + tx];
  __syncthreads();
  for (int cc = ty; cc < 32; cc += 8)
    out[(size_t)(c0 + cc) * R + r0 + tx] = to_fp8(tile[tx][cc]);
}

// ---------------------------------------------------------------------------
// QKV GEMM, MX-fp8: C[M,N] = A[M,K](fp8,rm) @ Bt[N,K](fp8,rm)^T + bias
// 128x128 tile, BK=128 (same 32KB LDS as bf16 BK=64), 16x16x128 scaled MFMA.
// n-tile = one (part,head) full d-range: part 0/1 (Q/K) fused expmap0 (+1/sqrt(d)
// for Q); part 2 (V) stored transposed to Vt[bh][d][s] bf16.
// C/D layout is shape-determined (== 16x16x32): col=lane&15, row=(lane>>4)*4+reg.
// ---------------------------------------------------------------------------
__global__ __launch_bounds__(256, 3)
void gemm_qkv_fp8(const uint8_t* __restrict__ A, const uint8_t* __restrict__ Bt,
                  const float* __restrict__ bias, bf16* __restrict__ Qo,
                  bf16* __restrict__ Ko, bf16* __restrict__ Vto, int M, int N,
                  int K) {
  __shared__ uint8_t As[128 * 128];
  __shared__ uint8_t Bs[128 * 128];
  __shared__ float red[2][128];
  const int t = threadIdx.x;
  const int w = t >> 6, lane = t & 63;
  const int lm = lane & 15, qd = lane >> 4;
  const int m0 = blockIdx.x * 128, n0 = blockIdx.y * 128;
  const int wm = (w & 1) * 64, wn = (w >> 1) * 64;

  const uint8_t* Ag = A + (size_t)m0 * K;
  const uint8_t* Bg = Bt + (size_t)n0 * K;

  f4v acc[4][4];
  f4v zero = {0.f, 0.f, 0.f, 0.f};
#pragma unroll
  for (int i = 0; i < 4; i++)
#pragma unroll
    for (int j = 0; j < 4; j++) acc[i][j] = zero;

  for (int k0 = 0; k0 < K; k0 += 128) {
#pragma unroll
    for (int c = 0; c < 4; c++) {
      int s = c * 256 + t;
      int r = s >> 3;
      int kc = (s & 7) ^ (r & 7);  // xor-swizzle 16B chunks within the 128B row
      gload16(Ag + (size_t)r * K + k0 + kc * 16, &As[s * 16]);
      gload16(Bg + (size_t)r * K + k0 + kc * 16, &Bs[s * 16]);
    }
    __syncthreads();
    i8v af[4], bfr[4];
#pragma unroll
    for (int tm = 0; tm < 4; tm++) {
      int row = wm + tm * 16 + lm;
      int ch = (qd * 2) ^ (row & 7);          // lane's 32B = chunks ch, ch^1
      union { int4 q[2]; i8v v; } u;
      u.q[0] = *(const int4*)&As[row * 128 + ch * 16];
      u.q[1] = *(const int4*)&As[row * 128 + (ch ^ 1) * 16];
      af[tm] = u.v;
    }
#pragma unroll
    for (int tn = 0; tn < 4; tn++) {
      int row = wn + tn * 16 + lm;
      int ch = (qd * 2) ^ (row & 7);
      union { int4 q[2]; i8v v; } u;
      u.q[0] = *(const int4*)&Bs[row * 128 + ch * 16];
      u.q[1] = *(const int4*)&Bs[row * 128 + (ch ^ 1) * 16];
      bfr[tn] = u.v;
    }
#pragma unroll
    for (int tm = 0; tm < 4; tm++)
#pragma unroll
      for (int tn = 0; tn < 4; tn++)
        acc[tm][tn] = mfma_fp8(af[tm], bfr[tn], acc[tm][tn]);
    __syncthreads();
  }

  const int part = n0 >> 10;  // block-uniform: 0=Q, 1=K, 2=V
  const int hh = (n0 >> 7) & 7;
  if (part == 2) {
#pragma unroll
    for (int tm = 0; tm < 4; tm++)
#pragma unroll
      for (int tn = 0; tn < 4; tn++) {
        int d = wn + tn * 16 + lm;
        float bv = bias[n0 + d];
        int row0 = m0 + wm + tm * 16 + qd * 4;
        int b = row0 >> 10, s0 = row0 & 1023;
        bf16 vt[4];
#pragma unroll
        for (int r = 0; r < 4; r++) vt[r] = __float2bfloat16(acc[tm][tn][r] + bv);
        *(ushort4*)&Vto[((size_t)(b * 8 + hh)) * 131072 + (size_t)d * 1024 + s0] =
            *(ushort4*)vt;
      }
  } else {
    float bvs[4];
#pragma unroll
    for (int tn = 0; tn < 4; tn++) bvs[tn] = bias[n0 + wn + tn * 16 + lm];
    float ss[4][4];
#pragma unroll
    for (int tm = 0; tm < 4; tm++)
#pragma unroll
      for (int r = 0; r < 4; r++) {
        float s = 0.f;
#pragma unroll
        for (int tn = 0; tn < 4; tn++) {
          float v = acc[tm][tn][r] + bvs[tn];
          s += v * v;
        }
#pragma unroll
        for (int off = 1; off < 16; off <<= 1) s += __shfl_xor(s, off, 64);
        ss[tm][r] = s;
      }
    if (lm == 0) {
#pragma unroll
      for (int tm = 0; tm < 4; tm++)
#pragma unroll
        for (int r = 0; r < 4; r++)
          red[w >> 1][wm + tm * 16 + qd * 4 + r] = ss[tm][r];
    }
    __syncthreads();
    const float qsc = (part == 0) ? 0.08838834764831845f : 1.0f;  // 1/sqrt(128)
    float scr[4][4];
#pragma unroll
    for (int tm = 0; tm < 4; tm++)
#pragma unroll
      for (int r = 0; r < 4; r++) {
        int row = wm + tm * 16 + qd * 4 + r;
        float tot = red[0][row] + red[1][row];
        float nrm = fmaxf(sqrtf(tot), 1e-7f);
        scr[tm][r] = tanhf(nrm) / nrm * qsc;
      }
    bf16* dst = (part == 0) ? Qo : Ko;
#pragma unroll
    for (int tm = 0; tm < 4; tm++)
#pragma unroll
      for (int tn = 0; tn < 4; tn++) {
        int d = wn + tn * 16 + lm;
        int row0 = m0 + wm + tm * 16 + qd * 4;
        int b = row0 >> 10, s0 = row0 & 1023;
#pragma unroll
        for (int r = 0; r < 4; r++)
          dst[(((size_t)(b * 8 + hh)) * 1024 + s0 + r) * 128 + d] =
              __float2bfloat16((acc[tm][tn][r] + bvs[tn]) * scr[tm][r]);
      }
  }
}

// ---------------------------------------------------------------------------
// GEMM (bf16): C[M,N] = A[M,K] @ Bt[N,K]^T + bias, fp32 out. (final projection)
// ---------------------------------------------------------------------------
__global__ __launch_bounds__(256, 3)
void gemm_bt(const bf16* __restrict__ A, const bf16* __restrict__ Bt,
             const float* __restrict__ bias, float* __restrict__ Cf, int M, int N,
             int K) {
  __shared__ bf16 As[128 * 64];
  __shared__ bf16 Bs[128 * 64];
  const int t = threadIdx.x;
  const int w = t >> 6, lane = t & 63;
  const int lm = lane & 15, qd = lane >> 4;
  const int m0 = blockIdx.x * 128, n0 = blockIdx.y * 128;
  const int wm = (w & 1) * 64, wn = (w >> 1) * 64;

  const bf16* Ag = A + (size_t)m0 * K;
  const bf16* Bg = Bt + (size_t)n0 * K;

  f4v acc[4][4];
  f4v zero = {0.f, 0.f, 0.f, 0.f};
#pragma unroll
  for (int i = 0; i < 4; i++)
#pragma unroll
    for (int j = 0; j < 4; j++) acc[i][j] = zero;

  for (int k0 = 0; k0 < K; k0 += 64) {
#pragma unroll
    for (int c = 0; c < 4; c++) {
      int s = c * 256 + t;
      int r = s >> 3;
      int kc = (s & 7) ^ (r & 7);
      gload16(Ag + (size_t)r * K + k0 + kc * 8, &As[s * 8]);
      gload16(Bg + (size_t)r * K + k0 + kc * 8, &Bs[s * 8]);
    }
    __syncthreads();
#pragma unroll
    for (int ks = 0; ks < 2; ks++) {
      b8 af[4], bfr[4];
#pragma unroll
      for (int tm = 0; tm < 4; tm++) {
        int row = wm + tm * 16 + lm;
        int ch = (ks * 4 + qd) ^ (row & 7);
        af[tm] = *(const b8*)&As[row * 64 + ch * 8];
      }
#pragma unroll
      for (int tn = 0; tn < 4; tn++) {
        int row = wn + tn * 16 + lm;
        int ch = (ks * 4 + qd) ^ (row & 7);
        bfr[tn] = *(const b8*)&Bs[row * 64 + ch * 8];
      }
#pragma unroll
      for (int tm = 0; tm < 4; tm++)
#pragma unroll
        for (int tn = 0; tn < 4; tn++)
          acc[tm][tn] = mfma_bf16(af[tm], bfr[tn], acc[tm][tn]);
    }
    __syncthreads();
  }

#pragma unroll
  for (int tm = 0; tm < 4; tm++)
#pragma unroll
    for (int tn = 0; tn < 4; tn++) {
      int col = n0 + wn + tn * 16 + lm;
      float bv = bias[col];
#pragma unroll
      for (int r = 0; r < 4; r++) {
        int row = m0 + wm + tm * 16 + qd * 4 + r;
        Cf[(size_t)row * N + col] = acc[tm][tn][r] + bv;
      }
    }
}

// ---------------------------------------------------------------------------
// Flash attention, no-max softmax (|score| <= 1/sqrt(128); exp in [0.915,1.092]).
// l via MFMA against all-ones B. grid (64 bh, 8 qt) => same-bh same-XCD.
// 4 waves x 32 q-rows; K-fragments loaded once and shared across both m-tiles.
// ---------------------------------------------------------------------------
__global__ __launch_bounds__(256, 2)
void attn_kernel(const bf16* __restrict__ Qf, const bf16* __restrict__ Kf,
                 const bf16* __restrict__ Vt, bf16* __restrict__ O) {
  __shared__ bf16 smem[24576];            // 49152 B
  bf16* Ks = smem;                        // [64 s'][128 d] chunk-swizzled
  bf16* Vs = smem + 8192;                 // [128 d][64 s'] chunk-swizzled
  bf16* Ps = smem + 16384;                // [4 waves][32 q][64 s'] perm-swizzled
  const int t = threadIdx.x, w = t >> 6, lane = t & 63;
  const int lm = lane & 15, qd = lane >> 4;
  const int bh = blockIdx.x, qt = blockIdx.y;
  const bf16* Qg = Qf + ((size_t)bh * 1024 + qt * 128) * 128;
  const bf16* Kg = Kf + (size_t)bh * 131072;
  const bf16* Vg = Vt + (size_t)bh * 131072;
  bf16* Pw = Ps + w * 2048;

  b8 qfr[2][4];
#pragma unroll
  for (int mt = 0; mt < 2; mt++)
#pragma unroll
    for (int ks = 0; ks < 4; ks++)
      qfr[mt][ks] =
          *(const b8*)(Qg + (size_t)(w * 32 + mt * 16 + lm) * 128 + ks * 32 + qd * 8);

  f4v o[2][8];
  f4v lacc[2];
  f4v zero = {0.f, 0.f, 0.f, 0.f};
#pragma unroll
  for (int mt = 0; mt < 2; mt++) {
    lacc[mt] = zero;
#pragma unroll
    for (int i = 0; i < 8; i++) o[mt][i] = zero;
  }
  union { s8v s; b8 b; } uo;
#pragma unroll
  for (int i = 0; i < 8; i++) uo.s[i] = 0x3F80;  // bf16 1.0
  const b8 ones = uo.b;

  for (int kt = 0; kt < 16; kt++) {
    __syncthreads();
#pragma unroll
    for (int c = 0; c < 4; c++) {
      int s = c * 256 + t;
      int r = s >> 4;
      int kc = (s & 15) ^ (r & 7);
      gload16(Kg + (size_t)(kt * 64 + r) * 128 + kc * 8, &Ks[s * 8]);
      int rv = s >> 3;
      int kv = (s & 7) ^ (rv & 7);
      gload16(Vg + (size_t)rv * 1024 + kt * 64 + kv * 8, &Vs[s * 8]);
    }
    __syncthreads();

    // scores: K frags read ONCE, used by both m-tiles
    f4v sc[2][4];
#pragma unroll
    for (int mt = 0; mt < 2; mt++)
#pragma unroll
      for (int tn = 0; tn < 4; tn++) sc[mt][tn] = zero;
#pragma unroll
    for (int tn = 0; tn < 4; tn++) {
      int krow = tn * 16 + lm;
#pragma unroll
      for (int ks = 0; ks < 4; ks++) {
        int ch = (ks * 4 + qd) ^ (krow & 7);
        b8 kfr = *(const b8*)&Ks[krow * 128 + ch * 8];
        sc[0][tn] = mfma_bf16(qfr[0][ks], kfr, sc[0][tn]);
        sc[1][tn] = mfma_bf16(qfr[1][ks], kfr, sc[1][tn]);
      }
    }
    // P = exp(s) -> LDS (perm swizzle (q>>1)&7)
#pragma unroll
    for (int mt = 0; mt < 2; mt++)
#pragma unroll
      for (int tn = 0; tn < 4; tn++)
#pragma unroll
        for (int r = 0; r < 4; r++) {
          int qi = mt * 16 + qd * 4 + r;
          int ch = (tn * 2 + (lm >> 3)) ^ ((qi >> 1) & 7);
          Pw[qi * 64 + ch * 8 + (lm & 7)] = __float2bfloat16(__expf(sc[mt][tn][r]));
        }

    b8 pa[2][2];
#pragma unroll
    for (int mt = 0; mt < 2; mt++)
#pragma unroll
      for (int kv2 = 0; kv2 < 2; kv2++) {
        int qi = mt * 16 + lm;
        int ch = (kv2 * 4 + qd) ^ ((lm >> 1) & 7);
        pa[mt][kv2] = *(const b8*)&Pw[qi * 64 + ch * 8];
      }
#pragma unroll
    for (int mt = 0; mt < 2; mt++)
#pragma unroll
      for (int kv2 = 0; kv2 < 2; kv2++)
        lacc[mt] = mfma_bf16(pa[mt][kv2], ones, lacc[mt]);
#pragma unroll
    for (int tnd = 0; tnd < 8; tnd++) {
      int drow = tnd * 16 + lm;
#pragma unroll
      for (int kv2 = 0; kv2 < 2; kv2++) {
        int ch = (kv2 * 4 + qd) ^ (drow & 7);
        b8 vfr = *(const b8*)&Vs[drow * 64 + ch * 8];
#pragma unroll
        for (int mt = 0; mt < 2; mt++)
          o[mt][tnd] = mfma_bf16(pa[mt][kv2], vfr, o[mt][tnd]);
      }
    }
  }

  const int b = bh >> 3, h = bh & 7;
#pragma unroll
  for (int mt = 0; mt < 2; mt++) {
    float rinv[4];
#pragma unroll
    for (int r = 0; r < 4; r++) rinv[r] = 1.0f / lacc[mt][r];
#pragma unroll
    for (int tnd = 0; tnd < 8; tnd++) {
      int d = tnd * 16 + lm;
#pragma unroll
      for (int r = 0; r < 4; r++) {
        int sIdx = qt * 128 + w * 32 + mt * 16 + qd * 4 + r;
        O[((size_t)b * 1024 + sIdx) * 1024 + h * 128 + d] =
            __float2bfloat16(o[mt][tnd][r] * rinv[r]);
      }
    }
  }
}

// ---------------------------------------------------------------------------
// update: m = o @ W_pinv + b_pinv (rank-8), upd = m @ W_attn[l] + b_attn[l],
// cur += upd, curb = bf16(cur), curf8 = fp8(cur).
// ---------------------------------------------------------------------------
__global__ __launch_bounds__(256)
void update_kernel(const bf16* __restrict__ O, const float* __restrict__ Wpinv,
                   const float* __restrict__ bpinv, const float* __restrict__ Wattn,
                   const float* __restrict__ battn, float* __restrict__ cur,
                   bf16* __restrict__ curb, uint8_t* __restrict__ curf8) {
  const int row = blockIdx.x;
  const int t = threadIdx.x, w = t >> 6, lane = t & 63;
  const int h0 = t * 4;
  const bf16* orow = O + (size_t)row * 1024;

  bf16 ob[4];
  *(ushort4*)ob = *(const ushort4*)(orow + h0);
  float ov[4];
#pragma unroll
  for (int i = 0; i < 4; i++) ov[i] = __bfloat162float(ob[i]);

  float acc[8];
#pragma unroll
  for (int j = 0; j < 8; j++) acc[j] = 0.f;
#pragma unroll
  for (int i = 0; i < 4; i++) {
    float4 wa = *(const float4*)(Wpinv + (size_t)(h0 + i) * 8);
    float4 wb = *(const float4*)(Wpinv + (size_t)(h0 + i) * 8 + 4);
    acc[0] += ov[i] * wa.x; acc[1] += ov[i] * wa.y;
    acc[2] += ov[i] * wa.z; acc[3] += ov[i] * wa.w;
    acc[4] += ov[i] * wb.x; acc[5] += ov[i] * wb.y;
    acc[6] += ov[i] * wb.z; acc[7] += ov[i] * wb.w;
  }
#pragma unroll
  for (int j = 0; j < 8; j++)
#pragma unroll
    for (int off = 32; off; off >>= 1) acc[j] += __shfl_xor(acc[j], off, 64);
  __shared__ float sm[4][8];
  if (lane == 0) {
#pragma unroll
    for (int j = 0; j < 8; j++) sm[w][j] = acc[j];
  }
  __syncthreads();
  float mv[8];
#pragma unroll
  for (int j = 0; j < 8; j++)
    mv[j] = sm[0][j] + sm[1][j] + sm[2][j] + sm[3][j] + bpinv[j];

  float u[4];
#pragma unroll
  for (int i = 0; i < 4; i++) u[i] = battn[h0 + i];
#pragma unroll
  for (int j = 0; j < 8; j++) {
    float4 wv = *(const float4*)(Wattn + (size_t)j * 1024 + h0);
    u[0] += mv[j] * wv.x; u[1] += mv[j] * wv.y;
    u[2] += mv[j] * wv.z; u[3] += mv[j] * wv.w;
  }
  float4 c4 = *(float4*)(cur + (size_t)row * 1024 + h0);
  c4.x += u[0]; c4.y += u[1]; c4.z += u[2]; c4.w += u[3];
  *(float4*)(cur + (size_t)row * 1024 + h0) = c4;
  bf16 cb[4];
  cb[0] = __float2bfloat16(c4.x); cb[1] = __float2bfloat16(c4.y);
  cb[2] = __float2bfloat16(c4.z); cb[3] = __float2bfloat16(c4.w);
  *(ushort4*)(curb + (size_t)row * 1024 + h0) = *(ushort4*)cb;
  uint32_t p = (uint32_t)to_fp8(c4.x) | ((uint32_t)to_fp8(c4.y) << 8) |
               ((uint32_t)to_fp8(c4.z) << 16) | ((uint32_t)to_fp8(c4.w) << 24);
  *(uint32_t*)(curf8 + (size_t)row * 1024 + h0) = p;
}

// ---------------------------------------------------------------------------
extern "C" void kernel_launch(void* const* d_in, const int* in_sizes, int n_in,
                              void* d_out, int out_size, void* d_ws, size_t ws_size,
                              hipStream_t stream) {
  const float* x      = (const float*)d_in[0];
  const float* W_qkv  = (const float*)d_in[1];
  const float* b_qkv  = (const float*)d_in[2];
  const float* W_pinv = (const float*)d_in[3];
  const float* b_pinv = (const float*)d_in[4];
  const float* W_attn = (const float*)d_in[5];
  const float* b_attn = (const float*)d_in[6];
  const float* W_out  = (const float*)d_in[7];
  const float* b_out  = (const float*)d_in[8];

  char* ws = (char*)d_ws;
  size_t off = 0;
  auto alloc = [&](size_t bytes) -> void* {
    void* p = ws + off;
    off += (bytes + 255) & ~(size_t)255;
    return p;
  };
  float* cur     = (float*)alloc((size_t)8192 * 1024 * 4);    // 32MB
  bf16* curb     = (bf16*)alloc((size_t)8192 * 1024 * 2);     // 16MB
  uint8_t* curf8 = (uint8_t*)alloc((size_t)8192 * 1024);      // 8MB
  uint8_t* Wqkv8 = (uint8_t*)alloc((size_t)3072 * 1024);      // 3MB [3072][1024] fp8
  bf16* Woutt    = (bf16*)alloc((size_t)1024 * 1024 * 2);     // 2MB
  bf16* Q        = (bf16*)alloc((size_t)8192 * 1024 * 2);     // 16MB [B,H,S,HD] flowed
  bf16* Kt       = (bf16*)alloc((size_t)8192 * 1024 * 2);     // 16MB [B,H,S,HD] flowed
  bf16* Vt       = (bf16*)alloc((size_t)8192 * 1024 * 2);     // 16MB [B,H,HD,S]
  bf16* O        = (bf16*)alloc((size_t)8192 * 1024 * 2);     // 16MB
  (void)ws_size; (void)in_sizes; (void)n_in; (void)out_size;

  prep_kernel<<<8192, 256, 0, stream>>>(x, cur, curb, curf8);
  transpose_cast_fp8<<<dim3(96, 32), 256, 0, stream>>>(W_qkv, Wqkv8, 1024, 3072);
  transpose_cast<<<dim3(32, 32), 256, 0, stream>>>(W_out, Woutt, 1024, 1024);

  for (int l = 0; l < 3; l++) {
    gemm_qkv_fp8<<<dim3(64, 24), 256, 0, stream>>>(curf8, Wqkv8, b_qkv, Q, Kt, Vt,
                                                   8192, 3072, 1024);
    attn_kernel<<<dim3(64, 8), 256, 0, stream>>>(Q, Kt, Vt, O);
    update_kernel<<<8192, 256, 0, stream>>>(O, W_pinv, b_pinv,
                                            W_attn + (size_t)l * 8 * 1024,
                                            b_attn + (size_t)l * 1024, cur, curb,
                                            curf8);
  }
  gemm_bt<<<dim3(64, 8), 256, 0, stream>>>(curb, Woutt, b_out, (float*)d_out, 8192,
                                           1024, 1024);
}